// Round 8
// baseline (426.352 us; speedup 1.0000x reference)
//
#include <hip/hip_runtime.h>
#include <float.h>

// B=4, S=2048, D=1024, H=16, hd=64. bf16 MFMA pipeline:
//   cast_x, transpose_cast(w_qkv), transpose_cast(w_out)
//   gemm_qkv (MFMA 128x128, C^T orientation for q/k packed stores)
//        -> qN (pre-scaled by 1/8*log2e), kN [bh][S][64], vT [bh][64][S]
//   attn (MFMA flash, paired causal q-tiles (y, 31-y) -> UNIFORM block duration,
//         K LDS double-buffer w/ 1-iter prefetch, 1 barrier/iter, V global->VGPR)
//   gemm_out (MFMA 128x128, C^T orientation, float4 stores) -> out fp32

#define SEQ   2048
#define DIM   1024
#define NH    16
#define HD    64
#define MROWS 8192
#define BHTOT 64

typedef __bf16 bf16_t;
typedef __bf16 bf16x4 __attribute__((ext_vector_type(4)));
typedef __bf16 bf16x8 __attribute__((ext_vector_type(8)));
typedef float  f32x4  __attribute__((ext_vector_type(4)));

typedef const __attribute__((address_space(1))) unsigned int* gas_ptr;
typedef __attribute__((address_space(3))) unsigned int* las_ptr;

__device__ __forceinline__ void gll16(const bf16_t* g, bf16_t* l) {
    __builtin_amdgcn_global_load_lds((gas_ptr)g, (las_ptr)l, 16, 0, 0);
}

// ---------------- cast kernels ----------------
__global__ __launch_bounds__(256) void cast_x_kernel(
    const float* __restrict__ x, bf16_t* __restrict__ xb)
{
    int i = (blockIdx.x * 256 + threadIdx.x) * 4;
    float4 v = *(const float4*)(x + i);
    bf16x4 o = { (bf16_t)v.x, (bf16_t)v.y, (bf16_t)v.z, (bf16_t)v.w };
    *(bf16x4*)(xb + i) = o;
}

// w [K][N] fp32 -> wT [N][K] bf16
__global__ __launch_bounds__(256) void transpose_cast_kernel(
    const float* __restrict__ w, bf16_t* __restrict__ wT, int K, int N)
{
    __shared__ float t[32][33];
    const int bk = blockIdx.x * 32, bn = blockIdx.y * 32;
    const int r = threadIdx.x >> 5, c = threadIdx.x & 31;
    #pragma unroll
    for (int i = 0; i < 4; i++)
        t[r + i * 8][c] = w[(size_t)(bk + r + i * 8) * N + bn + c];
    __syncthreads();
    #pragma unroll
    for (int i = 0; i < 4; i++)
        wT[(size_t)(bn + r + i * 8) * K + bk + c] = (bf16_t)t[c][r + i * 8];
}

// ---------------- GEMM qkv: 128x128 tile, BK=64, XOR-granule swizzle ----------------
__global__ __launch_bounds__(256) void gemm_qkv_kernel(
    const bf16_t* __restrict__ A,    // [8192][1024]
    const bf16_t* __restrict__ Bt,   // [3072][1024]
    bf16_t* __restrict__ qN, bf16_t* __restrict__ kN, bf16_t* __restrict__ vT)
{
    __shared__ bf16_t As[128 * 64];
    __shared__ bf16_t Bs[128 * 64];
    const int tid = threadIdx.x;
    const int lane = tid & 63, w = tid >> 6;
    const int quad = lane >> 4, l16 = lane & 15;
    const int wr = w >> 1, wc = w & 1;
    const int bm = blockIdx.x * 128, bn = blockIdx.y * 128;
    const int which = bn >> 10;   // 0=q, 1=k, 2=v (uniform per block)

    f32x4 acc[4][4] = {};

    for (int k0 = 0; k0 < DIM; k0 += 64) {
        __syncthreads();
        #pragma unroll
        for (int p = 0; p < 4; p++) {
            int flat = p * 256 + tid;
            int row = flat >> 3, g = flat & 7;
            int gs = g ^ (row & 7);
            gll16(A  + (size_t)(bm + row) * DIM + k0 + gs * 8, As + (size_t)(p * 256 + w * 64) * 8);
            gll16(Bt + (size_t)(bn + row) * DIM + k0 + gs * 8, Bs + (size_t)(p * 256 + w * 64) * 8);
        }
        __syncthreads();
        #pragma unroll
        for (int ks = 0; ks < 2; ks++) {
            bf16x8 af[4], bfv[4];
            #pragma unroll
            for (int mt = 0; mt < 4; mt++) {
                int row = wr * 64 + mt * 16 + l16;
                int g = (ks * 4 + quad) ^ (row & 7);
                af[mt] = *(const bf16x8*)(As + row * 64 + g * 8);
            }
            #pragma unroll
            for (int nt = 0; nt < 4; nt++) {
                int row = wc * 64 + nt * 16 + l16;
                int g = (ks * 4 + quad) ^ (row & 7);
                bfv[nt] = *(const bf16x8*)(Bs + row * 64 + g * 8);
            }
            if (which == 2) {
                #pragma unroll
                for (int mt = 0; mt < 4; mt++)
                    #pragma unroll
                    for (int nt = 0; nt < 4; nt++)
                        acc[mt][nt] = __builtin_amdgcn_mfma_f32_16x16x32_bf16(
                            af[mt], bfv[nt], acc[mt][nt], 0, 0, 0);
            } else {
                #pragma unroll
                for (int nt = 0; nt < 4; nt++)
                    #pragma unroll
                    for (int mt = 0; mt < 4; mt++)
                        acc[nt][mt] = __builtin_amdgcn_mfma_f32_16x16x32_bf16(
                            bfv[nt], af[mt], acc[nt][mt], 0, 0, 0);
            }
        }
    }

    if (which == 2) {
        #pragma unroll
        for (int mt = 0; mt < 4; mt++)
            #pragma unroll
            for (int nt = 0; nt < 4; nt++) {
                int row0 = bm + wr * 64 + mt * 16 + quad * 4;
                int b = row0 >> 11, s0 = row0 & 2047;
                int col = bn + wc * 64 + nt * 16 + l16;
                int nn = col & 1023, h = nn >> 6, d = nn & 63;
                int bh = b * NH + h;
                bf16x4 vv;
                #pragma unroll
                for (int r = 0; r < 4; r++) vv[r] = (bf16_t)acc[mt][nt][r];
                *(bf16x4*)(vT + ((size_t)bh * HD + d) * SEQ + s0) = vv;
            }
    } else {
        const float qsc = (which == 0) ? 0.18033688011112042f : 1.0f; // (1/8)*log2(e)
        bf16_t* dst = (which == 0) ? qN : kN;
        #pragma unroll
        for (int mt = 0; mt < 4; mt++) {
            int m = bm + wr * 64 + mt * 16 + l16;
            int b = m >> 11, s = m & 2047;
            #pragma unroll
            for (int nt = 0; nt < 4; nt++) {
                int n = bn + wc * 64 + nt * 16 + quad * 4;
                int nn = n & 1023, h = nn >> 6, d0 = nn & 63;
                int bh = b * NH + h;
                bf16x4 pk;
                #pragma unroll
                for (int r = 0; r < 4; r++) pk[r] = (bf16_t)(acc[nt][mt][r] * qsc);
                *(bf16x4*)(dst + ((size_t)bh * SEQ + s) * HD + d0) = pk;
            }
        }
    }
}

// C^T orientation: packed float4 stores.
__global__ __launch_bounds__(256) void gemm_out_kernel(
    const bf16_t* __restrict__ A,    // attnb [8192][1024]
    const bf16_t* __restrict__ Bt,   // woutT [1024][1024]
    float* __restrict__ out)
{
    __shared__ bf16_t As[128 * 64];
    __shared__ bf16_t Bs[128 * 64];
    const int tid = threadIdx.x;
    const int lane = tid & 63, w = tid >> 6;
    const int quad = lane >> 4, l16 = lane & 15;
    const int wr = w >> 1, wc = w & 1;
    const int bm = blockIdx.x * 128, bn = blockIdx.y * 128;

    f32x4 acc[4][4] = {};   // acc[nt][mt]: C^T

    for (int k0 = 0; k0 < DIM; k0 += 64) {
        __syncthreads();
        #pragma unroll
        for (int p = 0; p < 4; p++) {
            int flat = p * 256 + tid;
            int row = flat >> 3, g = flat & 7;
            int gs = g ^ (row & 7);
            gll16(A  + (size_t)(bm + row) * DIM + k0 + gs * 8, As + (size_t)(p * 256 + w * 64) * 8);
            gll16(Bt + (size_t)(bn + row) * DIM + k0 + gs * 8, Bs + (size_t)(p * 256 + w * 64) * 8);
        }
        __syncthreads();
        #pragma unroll
        for (int ks = 0; ks < 2; ks++) {
            bf16x8 af[4], bfv[4];
            #pragma unroll
            for (int mt = 0; mt < 4; mt++) {
                int row = wr * 64 + mt * 16 + l16;
                int g = (ks * 4 + quad) ^ (row & 7);
                af[mt] = *(const bf16x8*)(As + row * 64 + g * 8);
            }
            #pragma unroll
            for (int nt = 0; nt < 4; nt++) {
                int row = wc * 64 + nt * 16 + l16;
                int g = (ks * 4 + quad) ^ (row & 7);
                bfv[nt] = *(const bf16x8*)(Bs + row * 64 + g * 8);
            }
            #pragma unroll
            for (int nt = 0; nt < 4; nt++)
                #pragma unroll
                for (int mt = 0; mt < 4; mt++)
                    acc[nt][mt] = __builtin_amdgcn_mfma_f32_16x16x32_bf16(
                        bfv[nt], af[mt], acc[nt][mt], 0, 0, 0);
        }
    }

    #pragma unroll
    for (int mt = 0; mt < 4; mt++) {
        int m = bm + wr * 64 + mt * 16 + l16;
        #pragma unroll
        for (int nt = 0; nt < 4; nt++) {
            int n0 = bn + wc * 64 + nt * 16 + quad * 4;
            float4 ov = { acc[nt][mt][0], acc[nt][mt][1], acc[nt][mt][2], acc[nt][mt][3] };
            *(float4*)(out + (size_t)m * DIM + n0) = ov;
        }
    }
}

// ---------------- MFMA flash attention: paired causal q-tiles ----------------
// grid (BHTOT, 16). Block y handles q-tiles tA=y and tB=31-y (64 rows each):
// total active tile-units = (y+1)+(32-y) = 33 -> UNIFORM block duration, so
// 4 blocks/CU stay resident for the whole kernel (fixes R7's occupancy decay).
// Merged K-loop kt=0..tB; A-part active while kt<=tA (block-uniform branch).
// Wave w owns q-rows [w*16, w*16+16) of EACH tile. K LDS double-buffer with
// one-iteration prefetch distance (single barrier per iter); V global->VGPR.
// P^T in LDS (tile A rows 0..63, tile B rows 64..127), XOR-granule swizzle.
#define ISSUEK(kt_, buf_) do {                                                   \
    _Pragma("unroll")                                                            \
    for (int p_ = 0; p_ < 2; p_++) {                                             \
        int flat_ = p_ * 256 + tid;                                              \
        int row_ = flat_ >> 3, g_ = flat_ & 7;                                   \
        int gs_ = g_ ^ (row_ & 7);                                               \
        gll16(kbase + (size_t)((kt_) * 64 + row_) * HD + gs_ * 8,                \
              &Ks2[buf_][0] + (size_t)(p_ * 256 + w * 64) * 8);                  \
    }                                                                            \
} while (0)

__global__ __launch_bounds__(256, 4) void attn_kernel(
    const bf16_t* __restrict__ qN, const bf16_t* __restrict__ kN,
    const bf16_t* __restrict__ vT, bf16_t* __restrict__ attnb)
{
    __shared__ __align__(16) bf16_t QPs[128 * 64];     // 16 KB: Q tiles A|B, then P^T A|B
    __shared__ __align__(16) bf16_t Ks2[2][64 * 64];   // 16 KB: K double buffer

    const int bh = blockIdx.x;
    const int y  = blockIdx.y;
    const int tA = y, tB = 31 - y;
    const int tid = threadIdx.x;
    const int lane = tid & 63, w = tid >> 6;
    const int quad = lane >> 4, l16 = lane & 15;

    const bf16_t* qbase = qN + (size_t)bh * SEQ * HD;
    const bf16_t* kbase = kN + (size_t)bh * SEQ * HD;
    const bf16_t* vbase = vT + (size_t)bh * HD * SEQ;

    // stage Q: local rows 0..63 = tile A, 64..127 = tile B (XOR-granule swizzle)
    #pragma unroll
    for (int p = 0; p < 4; p++) {
        int flat = p * 256 + tid;
        int row = flat >> 3, g = flat & 7;
        int gs = g ^ (row & 7);
        int grow = (row < 64) ? (tA * 64 + row) : (tB * 64 + (row - 64));
        gll16(qbase + (size_t)grow * HD + gs * 8,
              QPs + (size_t)(p * 256 + w * 64) * 8);
    }
    __syncthreads();                 // Q resident

    ISSUEK(0, 0);                    // K tile 0 in flight; drained at first loop barrier

    // Q fragments (B-operand; wave-private rows)
    bf16x8 qaA[2], qaB[2];
    #pragma unroll
    for (int ks = 0; ks < 2; ks++) {
        int rA = w * 16 + l16;
        int gA = (ks * 4 + quad) ^ (rA & 7);
        qaA[ks] = *(const bf16x8*)(QPs + rA * 64 + gA * 8);
        int rB = 64 + w * 16 + l16;
        int gB = (ks * 4 + quad) ^ (rB & 7);
        qaB[ks] = *(const bf16x8*)(QPs + rB * 64 + gB * 8);
    }

    f32x4 oA[4] = {}, oB[4] = {};    // O^T per tile: row d = dt*16+quad*4+r, col qrow = l16
    float lA = 0.f, lB = 0.f;

    const int rl = w * 16 + l16;     // wave-local qrow within a tile (0..63)
    const int qrowA = tA * 64 + rl;
    const int qrowB = tB * 64 + rl;

    for (int kt = 0; kt <= tB; kt++) {
        __syncthreads();             // K[kt&1] ready; opposite-parity buffer free

        // ---- V fragments for this kt (issued before K gll16 so PV waits with K in flight) ----
        bf16x8 vb[2][4];
        #pragma unroll
        for (int ks = 0; ks < 2; ks++)
            #pragma unroll
            for (int dt = 0; dt < 4; dt++)
                vb[ks][dt] = *(const bf16x8*)(
                    vbase + (size_t)(dt * 16 + l16) * SEQ + kt * 64 + ks * 32 + quad * 8);

        // ---- prefetch next K tile (in flight until next loop-top barrier) ----
        if (kt < tB) ISSUEK(kt + 1, (kt + 1) & 1);

        const bf16_t* Kb = &Ks2[kt & 1][0];
        bf16x8 kb[2][4];
        #pragma unroll
        for (int ks = 0; ks < 2; ks++)
            #pragma unroll
            for (int nt = 0; nt < 4; nt++) {
                int row = nt * 16 + l16;
                int g = (ks * 4 + quad) ^ (row & 7);
                kb[ks][nt] = *(const bf16x8*)(Kb + row * 64 + g * 8);
            }

        const bool actA = (kt <= tA);    // block-uniform

        // ================= tile B (always active) =================
        {
            f32x4 s[4] = {};
            #pragma unroll
            for (int ks = 0; ks < 2; ks++)
                #pragma unroll
                for (int nt = 0; nt < 4; nt++)
                    s[nt] = __builtin_amdgcn_mfma_f32_16x16x32_bf16(
                        kb[ks][nt], qaB[ks], s[nt], 0, 0, 0);

            const bool maskit = (kt == tB);
            #pragma unroll
            for (int nt = 0; nt < 4; nt++) {
                bf16x4 pk;
                #pragma unroll
                for (int r = 0; r < 4; r++) {
                    float pv;
                    if (maskit) {
                        int key = kt * 64 + nt * 16 + quad * 4 + r;
                        pv = (key <= qrowB) ? __builtin_amdgcn_exp2f(s[nt][r]) : 0.0f;
                    } else {
                        pv = __builtin_amdgcn_exp2f(s[nt][r]);
                    }
                    lB += pv;
                    pk[r] = (bf16_t)pv;
                }
                int lrow = 64 + rl;
                int gw = (nt * 2 + (quad >> 1)) ^ (lrow & 7);
                *(bf16x4*)(QPs + lrow * 64 + gw * 8 + (quad & 1) * 4) = pk;
            }
        }

        // ================= tile A (while kt <= tA) =================
        if (actA) {
            f32x4 s[4] = {};
            #pragma unroll
            for (int ks = 0; ks < 2; ks++)
                #pragma unroll
                for (int nt = 0; nt < 4; nt++)
                    s[nt] = __builtin_amdgcn_mfma_f32_16x16x32_bf16(
                        kb[ks][nt], qaA[ks], s[nt], 0, 0, 0);

            const bool maskit = (kt == tA);
            #pragma unroll
            for (int nt = 0; nt < 4; nt++) {
                bf16x4 pk;
                #pragma unroll
                for (int r = 0; r < 4; r++) {
                    float pv;
                    if (maskit) {
                        int key = kt * 64 + nt * 16 + quad * 4 + r;
                        pv = (key <= qrowA) ? __builtin_amdgcn_exp2f(s[nt][r]) : 0.0f;
                    } else {
                        pv = __builtin_amdgcn_exp2f(s[nt][r]);
                    }
                    lA += pv;
                    pk[r] = (bf16_t)pv;
                }
                int gw = (nt * 2 + (quad >> 1)) ^ (rl & 7);
                *(bf16x4*)(QPs + rl * 64 + gw * 8 + (quad & 1) * 4) = pk;
            }
        }

        // ================= PV for both tiles =================
        #pragma unroll
        for (int ks = 0; ks < 2; ks++) {
            int lrowB = 64 + rl;
            int grB = (ks * 4 + quad) ^ (lrowB & 7);
            bf16x8 pbB = *(const bf16x8*)(QPs + lrowB * 64 + grB * 8);
            #pragma unroll
            for (int dt = 0; dt < 4; dt++)
                oB[dt] = __builtin_amdgcn_mfma_f32_16x16x32_bf16(
                    vb[ks][dt], pbB, oB[dt], 0, 0, 0);
        }
        if (actA) {
            #pragma unroll
            for (int ks = 0; ks < 2; ks++) {
                int grA = (ks * 4 + quad) ^ (rl & 7);
                bf16x8 pbA = *(const bf16x8*)(QPs + rl * 64 + grA * 8);
                #pragma unroll
                for (int dt = 0; dt < 4; dt++)
                    oA[dt] = __builtin_amdgcn_mfma_f32_16x16x32_bf16(
                        vb[ks][dt], pbA, oA[dt], 0, 0, 0);
            }
        }
    }

    // ---- epilogue: reduce l across quads (lanes l16, +16, +32, +48 share qrow) ----
    const int b = bh >> 4, h = bh & 15;
    {
        float lsum = lA;
        lsum += __shfl_xor(lsum, 16, 64);
        lsum += __shfl_xor(lsum, 32, 64);
        float inv = 1.0f / lsum;
        #pragma unroll
        for (int dt = 0; dt < 4; dt++) {
            bf16x4 ov;
            #pragma unroll
            for (int r = 0; r < 4; r++) ov[r] = (bf16_t)(oA[dt][r] * inv);
            *(bf16x4*)(attnb + ((size_t)(b * SEQ + qrowA)) * DIM + h * HD + dt * 16 + quad * 4) = ov;
        }
    }
    {
        float lsum = lB;
        lsum += __shfl_xor(lsum, 16, 64);
        lsum += __shfl_xor(lsum, 32, 64);
        float inv = 1.0f / lsum;
        #pragma unroll
        for (int dt = 0; dt < 4; dt++) {
            bf16x4 ov;
            #pragma unroll
            for (int r = 0; r < 4; r++) ov[r] = (bf16_t)(oB[dt][r] * inv);
            *(bf16x4*)(attnb + ((size_t)(b * SEQ + qrowB)) * DIM + h * HD + dt * 16 + quad * 4) = ov;
        }
    }
}

extern "C" void kernel_launch(void* const* d_in, const int* in_sizes, int n_in,
                              void* d_out, int out_size, void* d_ws, size_t ws_size,
                              hipStream_t stream) {
    const float* x     = (const float*)d_in[0];
    const float* w_qkv = (const float*)d_in[1];
    const float* w_out = (const float*)d_in[2];
    float* out = (float*)d_out;

    bf16_t* xb    = (bf16_t*)d_ws;                          // 8192*1024
    bf16_t* wqkvT = xb    + (size_t)MROWS * DIM;            // 3072*1024
    bf16_t* woutT = wqkvT + (size_t)3 * DIM * DIM;          // 1024*1024
    bf16_t* qNb   = woutT + (size_t)DIM * DIM;              // 64*2048*64
    bf16_t* kNb   = qNb   + (size_t)BHTOT * SEQ * HD;
    bf16_t* vTb   = kNb   + (size_t)BHTOT * SEQ * HD;
    bf16_t* attnb = vTb   + (size_t)BHTOT * SEQ * HD;       // 8192*1024

    cast_x_kernel<<<MROWS * DIM / 1024, 256, 0, stream>>>(x, xb);
    transpose_cast_kernel<<<dim3(DIM / 32, 3 * DIM / 32), 256, 0, stream>>>(w_qkv, wqkvT, DIM, 3 * DIM);
    transpose_cast_kernel<<<dim3(DIM / 32, DIM / 32), 256, 0, stream>>>(w_out, woutT, DIM, DIM);
    gemm_qkv_kernel<<<dim3(MROWS / 128, 3 * DIM / 128), 256, 0, stream>>>(xb, wqkvT, qNb, kNb, vTb);
    attn_kernel<<<dim3(BHTOT, 16), 256, 0, stream>>>(qNb, kNb, vTb, attnb);
    gemm_out_kernel<<<dim3(MROWS / 128, DIM / 128), 256, 0, stream>>>(attnb, woutT, out);
}